// Round 1
// baseline (537.813 us; speedup 1.0000x reference)
//
#include <hip/hip_runtime.h>

// PolyConv: out[n,:] = Wx@x[n] + Wl@x[l[n]] + Wr@x[r[n]] + b   (N=1e6, D=64, O=64)
//
// R2 post-mortem: 230us/dispatch, HBM 3.05 TB/s (48% achievable), MfmaUtil 4%,
// VALUBusy 3.4%. In-flight bytes (12KB/wave, ~96KB/CU) >> Little's-law need, so
// NOT latency-bound: throughput-bound on random 256B gathers (2 lines/row) with
// LLC thrashing (x = 256MB = exactly LLC size; FETCH shows only ~50% absorbed).
// R3: gather bf16. Pass 1 converts x -> xb (bf16, 128MB, half the LLC) in d_ws;
// pass 2 gathers 128B rows (1 line), 6x16B loads/tile, each load IS an MFMA
// A-fragment (zero per-tile cvt VALU). Gather demand halves, LLC hit rate jumps.

typedef __bf16 bf16x8 __attribute__((ext_vector_type(8)));
typedef float floatx4 __attribute__((ext_vector_type(4)));

#define D 64
#define O 64
#define K3 192

// ---------------- Pass 1: x (f32) -> xb (bf16), warm the LLC with xb ----------------
__global__ __launch_bounds__(256) void convert_x_bf16(
    const float* __restrict__ x, __bf16* __restrict__ xb, long n8)
{
    long i = (long)blockIdx.x * 256 + threadIdx.x;
    const long stride = (long)gridDim.x * 256;
    for (; i < n8; i += stride) {
        // NT loads: x is read once, keep it out of the LLC so xb stays resident.
        floatx4 a = __builtin_nontemporal_load((const floatx4*)x + 2 * i);
        floatx4 b = __builtin_nontemporal_load((const floatx4*)x + 2 * i + 1);
        bf16x8 f;
        f[0] = (__bf16)a[0]; f[1] = (__bf16)a[1];
        f[2] = (__bf16)a[2]; f[3] = (__bf16)a[3];
        f[4] = (__bf16)b[0]; f[5] = (__bf16)b[1];
        f[6] = (__bf16)b[2]; f[7] = (__bf16)b[3];
        ((bf16x8*)xb)[i] = f;   // normal store: leave xb cached for pass 2
    }
}

// ---------------- Pass 2: bf16 gather + MFMA ----------------
__device__ __forceinline__ void issue_gather_bf16(bf16x8 (&v)[6],
                                                  const __bf16* __restrict__ xb,
                                                  int item, int li, int ri, int quad) {
    const __bf16* px = xb + (size_t)item * D + quad * 8;
    const __bf16* pl = xb + (size_t)li   * D + quad * 8;
    const __bf16* pr = xb + (size_t)ri   * D + quad * 8;
    // v[2k],v[2k+1] = A-fragments for k-chunks [k*32, k*32+32): direct MFMA operands.
    v[0] = *(const bf16x8*)(px); v[1] = *(const bf16x8*)(px + 32);
    v[2] = *(const bf16x8*)(pl); v[3] = *(const bf16x8*)(pl + 32);
    v[4] = *(const bf16x8*)(pr); v[5] = *(const bf16x8*)(pr + 32);
}

__device__ __forceinline__ void compute_store_bf16(const bf16x8 (&v)[6],
                                                   const bf16x8 (&bfrag)[6][4],
                                                   const float (&bi)[4],
                                                   float* __restrict__ out,
                                                   int base, int col, int quad) {
    floatx4 acc[4];
#pragma unroll
    for (int ct = 0; ct < 4; ++ct)
        acc[ct] = (floatx4){bi[ct], bi[ct], bi[ct], bi[ct]};
#pragma unroll
    for (int ct = 0; ct < 4; ++ct)
#pragma unroll
        for (int ks = 0; ks < 6; ++ks)
            acc[ct] = __builtin_amdgcn_mfma_f32_16x16x32_bf16(
                v[ks], bfrag[ks][ct], acc[ct], 0, 0, 0);

    float* orow = out + (size_t)base * O;
#pragma unroll
    for (int ct = 0; ct < 4; ++ct)
#pragma unroll
        for (int r = 0; r < 4; ++r) {
            int m = quad * 4 + r;
            __builtin_nontemporal_store(acc[ct][r],
                                        orow + (size_t)m * O + ct * 16 + col);
        }
}

__global__ __launch_bounds__(256, 2) void polyconv_bf16(
    const __bf16* __restrict__ xb,
    const int* __restrict__ lidx,
    const int* __restrict__ ridx,
    const float* __restrict__ W,
    const float* __restrict__ bias,
    float* __restrict__ out,
    int n_tiles, int total_waves)
{
    const int lane = threadIdx.x & 63;
    const int wave_id = blockIdx.x * (blockDim.x >> 6) + (threadIdx.x >> 6);
    const int col  = lane & 15;
    const int quad = lane >> 4;

    // B fragments: lane holds W[16*ct+col][ks*32 + quad*8 + j], j=0..7 (96 VGPRs)
    bf16x8 bfrag[6][4];
#pragma unroll
    for (int ct = 0; ct < 4; ++ct) {
        const float* wrow = W + (size_t)(ct * 16 + col) * K3 + quad * 8;
#pragma unroll
        for (int ks = 0; ks < 6; ++ks) {
            floatx4 w0 = *(const floatx4*)(wrow + ks * 32);
            floatx4 w1 = *(const floatx4*)(wrow + ks * 32 + 4);
            bf16x8 f;
            f[0] = (__bf16)w0[0]; f[1] = (__bf16)w0[1];
            f[2] = (__bf16)w0[2]; f[3] = (__bf16)w0[3];
            f[4] = (__bf16)w1[0]; f[5] = (__bf16)w1[1];
            f[6] = (__bf16)w1[2]; f[7] = (__bf16)w1[3];
            bfrag[ks][ct] = f;
        }
    }
    float bi[4];
#pragma unroll
    for (int ct = 0; ct < 4; ++ct) bi[ct] = bias[ct * 16 + col];

    const int stride = total_waves;
    int t = wave_id;
    if (t >= n_tiles) return;           // wave-uniform

    bf16x8 va[6], vb[6];
    int li_n = 0, ri_n = 0;

    // Prologue: gathers for tile t into va; prefetch idx for t+stride.
    {
        int item = t * 16 + col;
        int li = lidx[item], ri = ridx[item];
        issue_gather_bf16(va, xb, item, li, ri, quad);
    }
    int t1 = t + stride;
    if (t1 < n_tiles) { li_n = lidx[t1 * 16 + col]; ri_n = ridx[t1 * 16 + col]; }

    while (true) {
        // ---- phase A: state in va, issue next into vb ----
        if (t1 < n_tiles) {
            issue_gather_bf16(vb, xb, t1 * 16 + col, li_n, ri_n, quad);
            int t2 = t1 + stride;
            if (t2 < n_tiles) { li_n = lidx[t2 * 16 + col]; ri_n = ridx[t2 * 16 + col]; }
        }
        compute_store_bf16(va, bfrag, bi, out, t * 16, col, quad);
        t = t1; t1 += stride;
        if (t >= n_tiles) break;

        // ---- phase B: state in vb, issue next into va ----
        if (t1 < n_tiles) {
            issue_gather_bf16(va, xb, t1 * 16 + col, li_n, ri_n, quad);
            int t2 = t1 + stride;
            if (t2 < n_tiles) { li_n = lidx[t2 * 16 + col]; ri_n = ridx[t2 * 16 + col]; }
        }
        compute_store_bf16(vb, bfrag, bi, out, t * 16, col, quad);
        t = t1; t1 += stride;
        if (t >= n_tiles) break;
    }
}

// ---------------- Fallback: original f32 path (if workspace too small) ----------------
__device__ __forceinline__ void issue_gather_f32(floatx4 (&v)[12], const float* __restrict__ x,
                                                 int item, int li, int ri, int quad) {
    const float* px = x + (size_t)item * D + quad * 8;
    const float* pl = x + (size_t)li   * D + quad * 8;
    const float* pr = x + (size_t)ri   * D + quad * 8;
    v[0]  = *(const floatx4*)(px);      v[1]  = *(const floatx4*)(px + 4);
    v[2]  = *(const floatx4*)(px + 32); v[3]  = *(const floatx4*)(px + 36);
    v[4]  = *(const floatx4*)(pl);      v[5]  = *(const floatx4*)(pl + 4);
    v[6]  = *(const floatx4*)(pl + 32); v[7]  = *(const floatx4*)(pl + 36);
    v[8]  = *(const floatx4*)(pr);      v[9]  = *(const floatx4*)(pr + 4);
    v[10] = *(const floatx4*)(pr + 32); v[11] = *(const floatx4*)(pr + 36);
}

__device__ __forceinline__ void compute_store_f32(const floatx4 (&v)[12],
                                                  const bf16x8 (&bfrag)[6][4],
                                                  const float (&bi)[4],
                                                  float* __restrict__ out,
                                                  int base, int col, int quad) {
    bf16x8 afrag[6];
#pragma unroll
    for (int ks = 0; ks < 6; ++ks) {
        floatx4 a0 = v[2 * ks], a1 = v[2 * ks + 1];
        bf16x8 f;
        f[0] = (__bf16)a0[0]; f[1] = (__bf16)a0[1];
        f[2] = (__bf16)a0[2]; f[3] = (__bf16)a0[3];
        f[4] = (__bf16)a1[0]; f[5] = (__bf16)a1[1];
        f[6] = (__bf16)a1[2]; f[7] = (__bf16)a1[3];
        afrag[ks] = f;
    }
    floatx4 acc[4];
#pragma unroll
    for (int ct = 0; ct < 4; ++ct)
        acc[ct] = (floatx4){bi[ct], bi[ct], bi[ct], bi[ct]};
#pragma unroll
    for (int ct = 0; ct < 4; ++ct)
#pragma unroll
        for (int ks = 0; ks < 6; ++ks)
            acc[ct] = __builtin_amdgcn_mfma_f32_16x16x32_bf16(
                afrag[ks], bfrag[ks][ct], acc[ct], 0, 0, 0);

    float* orow = out + (size_t)base * O;
#pragma unroll
    for (int ct = 0; ct < 4; ++ct)
#pragma unroll
        for (int r = 0; r < 4; ++r) {
            int m = quad * 4 + r;
            __builtin_nontemporal_store(acc[ct][r],
                                        orow + (size_t)m * O + ct * 16 + col);
        }
}

__global__ __launch_bounds__(256, 2) void polyconv_kernel(
    const float* __restrict__ x,
    const int* __restrict__ lidx,
    const int* __restrict__ ridx,
    const float* __restrict__ W,
    const float* __restrict__ bias,
    float* __restrict__ out,
    int n_tiles, int total_waves)
{
    const int lane = threadIdx.x & 63;
    const int wave_id = blockIdx.x * (blockDim.x >> 6) + (threadIdx.x >> 6);
    const int col  = lane & 15;
    const int quad = lane >> 4;

    bf16x8 bfrag[6][4];
#pragma unroll
    for (int ct = 0; ct < 4; ++ct) {
        const float* wrow = W + (size_t)(ct * 16 + col) * K3 + quad * 8;
#pragma unroll
        for (int ks = 0; ks < 6; ++ks) {
            floatx4 w0 = *(const floatx4*)(wrow + ks * 32);
            floatx4 w1 = *(const floatx4*)(wrow + ks * 32 + 4);
            bf16x8 f;
            f[0] = (__bf16)w0[0]; f[1] = (__bf16)w0[1];
            f[2] = (__bf16)w0[2]; f[3] = (__bf16)w0[3];
            f[4] = (__bf16)w1[0]; f[5] = (__bf16)w1[1];
            f[6] = (__bf16)w1[2]; f[7] = (__bf16)w1[3];
            bfrag[ks][ct] = f;
        }
    }
    float bi[4];
#pragma unroll
    for (int ct = 0; ct < 4; ++ct) bi[ct] = bias[ct * 16 + col];

    const int stride = total_waves;
    int t = wave_id;
    if (t >= n_tiles) return;

    floatx4 va[12], vb[12];
    int li_n = 0, ri_n = 0;

    {
        int item = t * 16 + col;
        int li = lidx[item], ri = ridx[item];
        issue_gather_f32(va, x, item, li, ri, quad);
    }
    int t1 = t + stride;
    if (t1 < n_tiles) { li_n = lidx[t1 * 16 + col]; ri_n = ridx[t1 * 16 + col]; }

    while (true) {
        if (t1 < n_tiles) {
            issue_gather_f32(vb, x, t1 * 16 + col, li_n, ri_n, quad);
            int t2 = t1 + stride;
            if (t2 < n_tiles) { li_n = lidx[t2 * 16 + col]; ri_n = ridx[t2 * 16 + col]; }
        }
        compute_store_f32(va, bfrag, bi, out, t * 16, col, quad);
        t = t1; t1 += stride;
        if (t >= n_tiles) break;

        if (t1 < n_tiles) {
            issue_gather_f32(va, x, t1 * 16 + col, li_n, ri_n, quad);
            int t2 = t1 + stride;
            if (t2 < n_tiles) { li_n = lidx[t2 * 16 + col]; ri_n = ridx[t2 * 16 + col]; }
        }
        compute_store_f32(vb, bfrag, bi, out, t * 16, col, quad);
        t = t1; t1 += stride;
        if (t >= n_tiles) break;
    }
}

extern "C" void kernel_launch(void* const* d_in, const int* in_sizes, int n_in,
                              void* d_out, int out_size, void* d_ws, size_t ws_size,
                              hipStream_t stream) {
    const float* x  = (const float*)d_in[0];
    const int*   li = (const int*)d_in[1];
    const int*   ri = (const int*)d_in[2];
    const float* W  = (const float*)d_in[3];
    const float* b  = (const float*)d_in[4];
    float* out = (float*)d_out;

    const int n = in_sizes[1];          // N = 1,000,000
    const int n_tiles = n / 16;         // 62500
    const size_t need = (size_t)n * D * sizeof(__bf16);   // 128 MB

    if (d_ws != nullptr && ws_size >= need) {
        __bf16* xb = (__bf16*)d_ws;
        const long n8 = (long)n * D / 8;          // 8M bf16x8 chunks
        convert_x_bf16<<<2048, 256, 0, stream>>>(x, xb, n8);

        const int blocks = 1024;                  // persistent-stride; lands where regs allow
        const int total_waves = blocks * 4;
        polyconv_bf16<<<blocks, 256, 0, stream>>>(xb, li, ri, W, b, out,
                                                  n_tiles, total_waves);
    } else {
        const int blocks = 1024;
        const int total_waves = blocks * 4;
        polyconv_kernel<<<blocks, 256, 0, stream>>>(x, li, ri, W, b, out,
                                                    n_tiles, total_waves);
    }
}